// Round 13
// baseline (427.571 us; speedup 1.0000x reference)
//
#include <hip/hip_runtime.h>
#include <hip/hip_bf16.h>

typedef __attribute__((ext_vector_type(8))) short s8x;   // 8 bf16 = 4 VGPRs (MFMA A/B frag)
typedef __attribute__((ext_vector_type(4))) short s4x;   // 4 bf16 = 2 VGPRs (16x16x16 frag)
typedef __attribute__((ext_vector_type(4))) float f4x;   // MFMA C/D frag
typedef unsigned short u16;
typedef unsigned int u32;

#define T_ 1024
#define TC_ 2048
#define SCLOG2E 0.1803368801111243f   // 0.125 * log2(e), folded into q-GEMM for exp2 softmax

// fine-grained waitcnt (AITER pattern): wait for all but newest N VMEM ops
#define WAIT_VM(n) asm volatile("s_waitcnt vmcnt(" #n ")" ::: "memory")

__device__ __forceinline__ u16 f2bf(float f) {
    u32 u = __float_as_uint(f);
    return (u16)((u + 0x7fffu + ((u >> 16) & 1u)) >> 16);  // RNE
}

#if defined(__has_builtin)
#if __has_builtin(__builtin_amdgcn_cvt_pk_bf16_f32)
#define HAVE_PK 1
#endif
#if __has_builtin(__builtin_amdgcn_mfma_f32_16x16x16bf16_1k)
#define HAVE_MFMA16 1
#endif
#endif

// pack two fp32 -> two bf16 (RNE) in one u32; HW packed cvt when available
__device__ __forceinline__ u32 pack2bf(float a, float b) {
#ifdef HAVE_PK
    typedef __attribute__((ext_vector_type(2))) __bf16 bf2t;
    bf2t r = __builtin_amdgcn_cvt_pk_bf16_f32(a, b);
    u32 u;
    __builtin_memcpy(&u, &r, 4);
    return u;
#else
    return (u32)f2bf(a) | ((u32)f2bf(b) << 16);
#endif
}

// D = A(4bf16/lane) * B(4bf16/lane) + C   [v_mfma_f32_16x16x16_bf16]
__device__ __forceinline__ f4x mfma16(s4x a, s4x b, f4x c) {
#ifdef HAVE_MFMA16
    return __builtin_amdgcn_mfma_f32_16x16x16bf16_1k(a, b, c, 0, 0, 0);
#else
    f4x d = c;
    asm volatile("v_mfma_f32_16x16x16_bf16 %0, %1, %2, %0" : "+v"(d) : "v"(a), "v"(b));
    return d;
#endif
}

// async global->LDS, 16B per lane; LDS dst is wave-uniform base + lane*16
__device__ __forceinline__ void gload16(const void* g, void* l) {
    __builtin_amdgcn_global_load_lds((const __attribute__((address_space(1))) u32*)g,
                                     (__attribute__((address_space(3))) u32*)l, 16, 0, 0);
}

// ---- gamma = mean(|W|), 4 weights in one launch ----------------------------
__global__ __launch_bounds__(256) void absmean_k(const float* __restrict__ W0, const float* __restrict__ W1,
                                                 const float* __restrict__ W2, const float* __restrict__ W3,
                                                 float* __restrict__ gsum) {
    int wi = blockIdx.y;
    const float* W = (wi == 0) ? W0 : (wi == 1) ? W1 : (wi == 2) ? W2 : W3;
    const int n4 = (1024 * 1024) / 4;
    float s = 0.f;
    int stride = gridDim.x * blockDim.x;
    for (int i = blockIdx.x * blockDim.x + threadIdx.x; i < n4; i += stride) {
        float4 v = ((const float4*)W)[i];
        s += fabsf(v.x) + fabsf(v.y) + fabsf(v.z) + fabsf(v.w);
    }
#pragma unroll
    for (int off = 32; off; off >>= 1) s += __shfl_down(s, off, 64);
    __shared__ float ps[4];
    if ((threadIdx.x & 63) == 0) ps[threadIdx.x >> 6] = s;
    __syncthreads();
    if (threadIdx.x == 0) atomicAdd(gsum + wi, ps[0] + ps[1] + ps[2] + ps[3]);
}

// ---- merged prep: LN(x)->xn | ctx->bf16 | ternary quantize (one launch) ----
__global__ __launch_bounds__(256) void prep_k(
        const float* __restrict__ x, const float* __restrict__ lng, const float* __restrict__ lnb,
        u16* __restrict__ xn,
        const float* __restrict__ ctx, u16* __restrict__ ctxb,
        const float* __restrict__ W0, const float* __restrict__ W1,
        const float* __restrict__ W2, const float* __restrict__ W3,
        u16* __restrict__ D0, u16* __restrict__ D1, u16* __restrict__ D2, u16* __restrict__ D3,
        const float* __restrict__ gsum) {
    __shared__ float ps[8];
    int bx = blockIdx.x, t = threadIdx.x;
    if (bx < 4096) {                      // LayerNorm row bx
        int row = bx;
        float4 xv = ((const float4*)(x + (long)row * 1024))[t];
        float s = xv.x + xv.y + xv.z + xv.w;
        float s2 = xv.x * xv.x + xv.y * xv.y + xv.z * xv.z + xv.w * xv.w;
#pragma unroll
        for (int off = 32; off; off >>= 1) { s += __shfl_down(s, off, 64); s2 += __shfl_down(s2, off, 64); }
        if ((t & 63) == 0) { ps[t >> 6] = s; ps[4 + (t >> 6)] = s2; }
        __syncthreads();
        float S = ps[0] + ps[1] + ps[2] + ps[3];
        float S2 = ps[4] + ps[5] + ps[6] + ps[7];
        float mu = S * (1.f / 1024.f);
        float var = S2 * (1.f / 1024.f) - mu * mu;
        float rstd = rsqrtf(var + 1e-5f);
        float4 gv = ((const float4*)lng)[t];
        float4 bv = ((const float4*)lnb)[t];
        uint2 o;
        o.x = pack2bf((xv.x - mu) * rstd * gv.x + bv.x, (xv.y - mu) * rstd * gv.y + bv.y);
        o.y = pack2bf((xv.z - mu) * rstd * gv.z + bv.z, (xv.w - mu) * rstd * gv.w + bv.w);
        ((uint2*)(xn + (long)row * 1024))[t] = o;
    } else if (bx < 12288) {              // cast context
        int i = (bx - 4096) * 256 + t;
        float4 v = ((const float4*)ctx)[i];
        uint2 o = {pack2bf(v.x, v.y), pack2bf(v.z, v.w)};
        ((uint2*)ctxb)[i] = o;
    } else {                              // ternary quantize
        int wi = (bx - 12288) >> 10;
        const float* W = (wi == 0) ? W0 : (wi == 1) ? W1 : (wi == 2) ? W2 : W3;
        u16* D = (wi == 0) ? D0 : (wi == 1) ? D1 : (wi == 2) ? D2 : D3;
        float inv = 1.0f / (gsum[wi] * (1.0f / 1048576.0f) + 1e-5f);
        int i = ((bx - 12288) & 1023) * 256 + t;
        float4 wv = ((const float4*)W)[i];
        uint2 o;
        o.x = pack2bf(fminf(1.f, fmaxf(-1.f, rintf(wv.x * inv))),
                      fminf(1.f, fmaxf(-1.f, rintf(wv.y * inv))));
        o.y = pack2bf(fminf(1.f, fmaxf(-1.f, rintf(wv.z * inv))),
                      fminf(1.f, fmaxf(-1.f, rintf(wv.w * inv))));
        ((uint2*)D)[i] = o;
    }
}

// ---- uber GEMM: q (256 blk) | k/v interleaved (1024 blk) -------------------
// BK=32, 3 LDS buffers, 2-deep prefetch, s_barrier + vmcnt(4), fully unrolled.
__global__ __launch_bounds__(256) void gemm_fused(
        const u16* __restrict__ xn, const u16* __restrict__ ctxb,
        const u16* __restrict__ wtq, const u16* __restrict__ wtk, const u16* __restrict__ wtv,
        const float* __restrict__ bq, const float* __restrict__ bk, const float* __restrict__ bv,
        const float* __restrict__ gsum,
        u16* __restrict__ qb, u16* __restrict__ kb, u16* __restrict__ vtb) {
    __shared__ __align__(16) char smem[49152];   // 3 x (A 8K | B 8K); reused as 32K C^T tile (v)
    int tid = threadIdx.x;
    int w = tid >> 6, l = tid & 63, lq = l & 15, lh = l >> 4;
    int wm = (w >> 1) * 64, wn = (w & 1) * 64;
    int bx = blockIdx.x;
    int xcd = bx & 7;
    int prob, m0, n0, gidx;
    const u16 *A, *Wt;
    const float* bias;
    float sc;
    if (bx < 256) {
        int local = bx >> 3;              // 0..31
        prob = 0; A = xn; Wt = wtq; bias = bq; sc = SCLOG2E; gidx = 0;
        m0 = (xcd * 4 + (local & 3)) * 128;
        n0 = (local >> 2) * 128;
    } else {
        int b = bx - 256;                 // 0..1023
        int local3 = b >> 3;              // 0..127
        int kv = local3 & 1;              // k/v alternate -> share A-tile in L2
        int idx = local3 >> 1;            // 0..63
        prob = 1 + kv; A = ctxb;
        Wt = kv ? wtv : wtk; bias = kv ? bv : bk; sc = 1.0f; gidx = 1 + kv;
        m0 = (xcd * 8 + (idx & 7)) * 128;
        n0 = (idx >> 3) * 128;
    }
    int sp = tid >> 3, ss = tid & 7;
    int st = ss ^ (sp & 7);
    int r0 = sp * 2 + (st >> 2), c0 = st & 3;
    const u16* Ag0 = A + (long)(m0 + r0) * 1024 + c0 * 8;
    const u16* Ag1 = Ag0 + 64 * 1024;
    const u16* Bg0 = Wt + (long)(n0 + r0) * 1024 + c0 * 8;
    const u16* Bg1 = Bg0 + 64 * 1024;
    int aoff[4], boff[4];
#pragma unroll
    for (int i = 0; i < 4; i++) {
        int ar = wm + i * 16 + lq, ap = ar >> 1;
        aoff[i] = ap * 128 + (((((ar & 1) << 2) | lh) ^ (ap & 7)) * 16);
        int br = wn + i * 16 + lq, bp = br >> 1;
        boff[i] = bp * 128 + (((((br & 1) << 2) | lh) ^ (bp & 7)) * 16);
    }
    f4x acc[4][4] = {};
#define STAGE_G(kt, buf)                                                   \
    {                                                                      \
        char* Ad = smem + (buf) * 16384;                                   \
        char* Bd = Ad + 8192;                                              \
        gload16(Ag0 + (kt) * 32, Ad + tid * 16);                           \
        gload16(Ag1 + (kt) * 32, Ad + 4096 + tid * 16);                    \
        gload16(Bg0 + (kt) * 32, Bd + tid * 16);                           \
        gload16(Bg1 + (kt) * 32, Bd + 4096 + tid * 16);                    \
    }
    STAGE_G(0, 0);
    STAGE_G(1, 1);
#pragma unroll
    for (int kt = 0; kt < 32; kt++) {      // fully unrolled: kt compile-time
        if (kt < 31) { WAIT_VM(4); } else { WAIT_VM(0); }
        __builtin_amdgcn_s_barrier();
        if (kt + 2 < 32) STAGE_G(kt + 2, (kt + 2) % 3);
        const char* Ac = smem + (kt % 3) * 16384;
        const char* Bc = Ac + 8192;
        s8x af[4], bfr[4];
#pragma unroll
        for (int i = 0; i < 4; i++) {
            af[i] = *(const s8x*)(Ac + aoff[i]);
            bfr[i] = *(const s8x*)(Bc + boff[i]);
        }
#pragma unroll
        for (int i = 0; i < 4; i++)
#pragma unroll
            for (int j = 0; j < 4; j++)
                acc[i][j] = __builtin_amdgcn_mfma_f32_16x16x32_bf16(af[i], bfr[j], acc[i][j], 0, 0, 0);
    }
    float gamma = gsum[gidx] * (1.0f / 1048576.0f) * sc;
    if (prob < 2) {
        u16* outq = (prob == 0) ? qb : kb;
        int tshift = (prob == 0) ? 10 : 11;
        int tmask = (1 << tshift) - 1;
#pragma unroll
        for (int i = 0; i < 4; i++) {
            int gr = m0 + wm + i * 16 + lh * 4;
#pragma unroll
            for (int j = 0; j < 4; j++) {
                int gc = n0 + wn + j * 16 + lq;
                float bb = bias[gc] * sc;
                int h = gc >> 6, d = gc & 63;
#pragma unroll
                for (int r = 0; r < 4; r++) {
                    int row = gr + r;
                    int bidx = row >> tshift, tt = row & tmask;
                    outq[((((long)(bidx * 16 + h)) << tshift) + tt) * 64 + d] = f2bf(acc[i][j][r] * gamma + bb);
                }
            }
        }
    } else {
        // V^T epilogue: C tile -> LDS [col][tt] (swizzled) -> coalesced b128 stores
        __syncthreads();
        char* Ct = smem;
#pragma unroll
        for (int i = 0; i < 4; i++) {
            int tt = wm + i * 16 + lh * 4;
#pragma unroll
            for (int j = 0; j < 4; j++) {
                int c = wn + j * 16 + lq;
                float bb = bias[n0 + c];
                uint2 pk;
                pk.x = pack2bf(acc[i][j][0] * gamma + bb, acc[i][j][1] * gamma + bb);
                pk.y = pack2bf(acc[i][j][2] * gamma + bb, acc[i][j][3] * gamma + bb);
                int slot = (tt >> 3) ^ (c & 15);
                *(uint2*)(Ct + c * 256 + slot * 16 + (tt & 7) * 2) = pk;
            }
        }
        __syncthreads();
        int bb2 = m0 >> 11, t0 = m0 & 2047;
#pragma unroll
        for (int it = 0; it < 8; it++) {
            int e = it * 256 + tid;
            int c = e >> 4, ch = e & 15;
            int slot = ch ^ (c & 15);
            s8x v = *(const s8x*)(Ct + c * 256 + slot * 16);
            int gcg = n0 + c;
            int h = gcg >> 6, d = gcg & 63;
            *(s8x*)(vtb + ((long)((bb2 * 16 + h) * 64 + d)) * TC_ + t0 + ch * 8) = v;
        }
    }
}

// ---- O GEMM: out = x + attn @ WoT + bo, 128x64 tile, 3-buf, full unroll ----
__global__ __launch_bounds__(256) void gemm_o(const u16* __restrict__ A, const u16* __restrict__ Wt,
                                              const float* __restrict__ bias, const float* __restrict__ gsum,
                                              const float* __restrict__ residual, float* __restrict__ outr) {
    __shared__ __align__(16) char smem[36864];   // 3 x (A 8K | B 4K)
    int tid = threadIdx.x;
    int w = tid >> 6, l = tid & 63, lq = l & 15, lh = l >> 4;
    int wm = (w >> 1) * 64, wn = (w & 1) * 32;
    int bx = blockIdx.x;
    int xcd = bx & 7, local = bx >> 3;
    int m0 = (xcd * 4 + (local & 3)) * 128;
    int n0 = (local >> 2) * 64;
    int sp = tid >> 3, ss = tid & 7;
    int st = ss ^ (sp & 7);
    int r0 = sp * 2 + (st >> 2), c0 = st & 3;
    const u16* Ag0 = A + (long)(m0 + r0) * 1024 + c0 * 8;
    const u16* Ag1 = Ag0 + 64 * 1024;
    const u16* Bg0 = Wt + (long)(n0 + r0) * 1024 + c0 * 8;
    int aoff[4], boff[2];
#pragma unroll
    for (int i = 0; i < 4; i++) {
        int ar = wm + i * 16 + lq, ap = ar >> 1;
        aoff[i] = ap * 128 + (((((ar & 1) << 2) | lh) ^ (ap & 7)) * 16);
    }
#pragma unroll
    for (int j = 0; j < 2; j++) {
        int br = wn + j * 16 + lq, bp = br >> 1;
        boff[j] = bp * 128 + (((((br & 1) << 2) | lh) ^ (bp & 7)) * 16);
    }
    f4x acc[4][2] = {};
#define STAGE_O(kt, buf)                                                   \
    {                                                                      \
        char* Ad = smem + (buf) * 12288;                                   \
        char* Bd = Ad + 8192;                                              \
        gload16(Ag0 + (kt) * 32, Ad + tid * 16);                           \
        gload16(Ag1 + (kt) * 32, Ad + 4096 + tid * 16);                    \
        gload16(Bg0 + (kt) * 32, Bd + tid * 16);                           \
    }
    STAGE_O(0, 0);
    STAGE_O(1, 1);
#pragma unroll
    for (int kt = 0; kt < 32; kt++) {
        if (kt < 31) { WAIT_VM(3); } else { WAIT_VM(0); }
        __builtin_amdgcn_s_barrier();
        if (kt + 2 < 32) STAGE_O(kt + 2, (kt + 2) % 3);
        const char* Ac = smem + (kt % 3) * 12288;
        const char* Bc = Ac + 8192;
        s8x af[4], bfr[2];
#pragma unroll
        for (int i = 0; i < 4; i++) af[i] = *(const s8x*)(Ac + aoff[i]);
#pragma unroll
        for (int j = 0; j < 2; j++) bfr[j] = *(const s8x*)(Bc + boff[j]);
#pragma unroll
        for (int i = 0; i < 4; i++)
#pragma unroll
            for (int j = 0; j < 2; j++)
                acc[i][j] = __builtin_amdgcn_mfma_f32_16x16x32_bf16(af[i], bfr[j], acc[i][j], 0, 0, 0);
    }
    float gamma = gsum[3] * (1.0f / 1048576.0f);
#pragma unroll
    for (int i = 0; i < 4; i++) {
        int gr = m0 + wm + i * 16 + lh * 4;
#pragma unroll
        for (int j = 0; j < 2; j++) {
            int gc = n0 + wn + j * 16 + lq;
            float bb = bias[gc];
#pragma unroll
            for (int r = 0; r < 4; r++) {
                long idx = (long)(gr + r) * 1024 + gc;
                outr[idx] = residual[idx] + acc[i][j][r] * gamma + bb;
            }
        }
    }
}

// ---- flash attention v6: 256 thr (4 waves), 128 q/block, 32 q/wave.
// NO P LDS round-trip: S^T C-layout (k=quad*4+r, q=lane&15) IS the B-operand
// layout of v_mfma_f32_16x16x16_bf16, so P feeds PV directly from registers;
// A-operand = V^T frags (b64 reads). O^T accumulated; row-sums via VALU adds.
// 3 KV buffers, 2-deep prefetch, vmcnt(4) + s_barrier, fully unrolled.
__global__ __launch_bounds__(256) void attn_k(const u16* __restrict__ qh, const u16* __restrict__ kh,
                                              const u16* __restrict__ vth, u16* __restrict__ attn) {
    __shared__ __align__(16) char smem[49152];   // 3 x (K 8K | V 8K); Q staged in buf2
    int tid = threadIdx.x, w = tid >> 6, l = tid & 63, lq = l & 15, lh = l >> 4;
    int bh = blockIdx.x, q0 = blockIdx.y * 128;
    const u16* qp = qh + ((long)bh * T_ + q0) * 64;
    const u16* kp = kh + (long)bh * TC_ * 64;
    const u16* vp = vth + (long)bh * 64 * TC_;
    // stage Q 128x64 (swizzled) into buf2 region
#pragma unroll
    for (int i = 0; i < 4; i++) {
        int cid = i * 256 + tid;
        int r = cid >> 3, c = (cid & 7) ^ (r & 7);
        gload16(qp + r * 64 + c * 8, smem + 32768 + cid * 16);
    }
    __syncthreads();
    s8x qf[2][2];   // B-operand (16x16x32): Q[q = w*32 + nb*16 + lq][d]
#pragma unroll
    for (int nb = 0; nb < 2; nb++)
#pragma unroll
        for (int dh = 0; dh < 2; dh++) {
            int qrow = w * 32 + nb * 16 + lq;
            int ch = (dh * 4 + lh) ^ (qrow & 7);
            qf[nb][dh] = *(const s8x*)(smem + 32768 + qrow * 128 + ch * 16);
        }
    __syncthreads();   // all Q reads done before buf2 is re-staged (at kt=0)
#define STAGE_KV(kt, buf)                                                          \
    {                                                                              \
        char* Kb = smem + (buf) * 16384;                                           \
        char* Vb = Kb + 8192;                                                      \
        int r = tid >> 3, c = (tid & 7) ^ (r & 7);                                 \
        gload16(kp + ((kt) * 64 + r) * 64 + c * 8, Kb + tid * 16);                 \
        gload16(kp + ((kt) * 64 + r + 32) * 64 + c * 8, Kb + 4096 + tid * 16);     \
        gload16(vp + (long)r * TC_ + (kt) * 64 + c * 8, Vb + tid * 16);            \
        gload16(vp + (long)(r + 32) * TC_ + (kt) * 64 + c * 8, Vb + 4096 + tid * 16); \
    }
    STAGE_KV(0, 0);
    STAGE_KV(1, 1);
    f4x oaccT[2][4] = {};   // O^T[d_local][q] per (nb, nd)
    float lsum[2] = {};
    // lane-fixed V-frag offsets: byte = vr*128 + ((ni*2+(lh>>1))^(vr&7))*16 + (lh&1)*8
    int voff[4][4];
#pragma unroll
    for (int nd = 0; nd < 4; nd++)
#pragma unroll
        for (int ni = 0; ni < 4; ni++) {
            int vr = nd * 16 + lq;
            voff[nd][ni] = vr * 128 + (((ni * 2 + (lh >> 1)) ^ (vr & 7)) * 16) + (lh & 1) * 8;
        }
    int koff[4][2];
#pragma unroll
    for (int ni = 0; ni < 4; ni++) {
        int kr = ni * 16 + lq;
        koff[ni][0] = kr * 128 + ((lh ^ (kr & 7)) * 16);
        koff[ni][1] = kr * 128 + (((4 + lh) ^ (kr & 7)) * 16);
    }
#pragma unroll
    for (int kt = 0; kt < 32; kt++) {
        if (kt < 31) { WAIT_VM(4); } else { WAIT_VM(0); }
        __builtin_amdgcn_s_barrier();
        if (kt + 2 < 32) STAGE_KV(kt + 2, (kt + 2) % 3);
        const char* Ksb = smem + (kt % 3) * 16384;
        const char* Vsb = Ksb + 8192;
#pragma unroll
        for (int ni = 0; ni < 4; ni++) {
            s8x a0 = *(const s8x*)(Ksb + koff[ni][0]);
            s8x a1 = *(const s8x*)(Ksb + koff[ni][1]);
            s4x pf[2];
#pragma unroll
            for (int nb = 0; nb < 2; nb++) {
                f4x zz = {0.f, 0.f, 0.f, 0.f};
                zz = __builtin_amdgcn_mfma_f32_16x16x32_bf16(a0, qf[nb][0], zz, 0, 0, 0);
                zz = __builtin_amdgcn_mfma_f32_16x16x32_bf16(a1, qf[nb][1], zz, 0, 0, 0);
                float e0 = __builtin_amdgcn_exp2f(zz[0]);
                float e1 = __builtin_amdgcn_exp2f(zz[1]);
                float e2 = __builtin_amdgcn_exp2f(zz[2]);
                float e3 = __builtin_amdgcn_exp2f(zz[3]);
                lsum[nb] += (e0 + e1) + (e2 + e3);
                u32 p01 = pack2bf(e0, e1), p23 = pack2bf(e2, e3);
                s4x pv;
                __builtin_memcpy(&pv, &p01, 4);
                __builtin_memcpy(((char*)&pv) + 4, &p23, 4);
                pf[nb] = pv;
            }
#pragma unroll
            for (int nd = 0; nd < 4; nd++) {
                s4x vf = *(const s4x*)(Vsb + voff[nd][ni]);
                oaccT[0][nd] = mfma16(vf, pf[0], oaccT[0][nd]);
                oaccT[1][nd] = mfma16(vf, pf[1], oaccT[1][nd]);
            }
        }
    }
    int b = bh >> 4, h = bh & 15;
#pragma unroll
    for (int nb = 0; nb < 2; nb++) {
        float s = lsum[nb];
        s += __shfl_xor(s, 16, 64);
        s += __shfl_xor(s, 32, 64);
        float rcp = 1.f / s;
        int q = q0 + w * 32 + nb * 16 + lq;
        u16* dst = attn + ((long)(b * T_ + q)) * 1024 + h * 64 + lh * 4;
#pragma unroll
        for (int nd = 0; nd < 4; nd++) {
            uint2 o;
            o.x = pack2bf(oaccT[nb][nd][0] * rcp, oaccT[nb][nd][1] * rcp);
            o.y = pack2bf(oaccT[nb][nd][2] * rcp, oaccT[nb][nd][3] * rcp);
            *(uint2*)(dst + nd * 16) = o;
        }
    }
}

extern "C" void kernel_launch(void* const* d_in, const int* in_sizes, int n_in,
                              void* d_out, int out_size, void* d_ws, size_t ws_size,
                              hipStream_t stream) {
    const float* x   = (const float*)d_in[0];
    const float* ctx = (const float*)d_in[1];
    const float* Wq  = (const float*)d_in[2];
    const float* bq  = (const float*)d_in[3];
    const float* Wk  = (const float*)d_in[4];
    const float* bk  = (const float*)d_in[5];
    const float* Wv  = (const float*)d_in[6];
    const float* bv  = (const float*)d_in[7];
    const float* Wo  = (const float*)d_in[8];
    const float* bo  = (const float*)d_in[9];
    const float* lng = (const float*)d_in[10];
    const float* lnb = (const float*)d_in[11];
    float* out = (float*)d_out;

    char* ws = (char*)d_ws;
    float* gsum = (float*)ws;
    size_t off = 256;
    u16* wtq  = (u16*)(ws + off); off += (size_t)1024 * 1024 * 2;
    u16* wtk  = (u16*)(ws + off); off += (size_t)1024 * 1024 * 2;
    u16* wtv  = (u16*)(ws + off); off += (size_t)1024 * 1024 * 2;
    u16* wto  = (u16*)(ws + off); off += (size_t)1024 * 1024 * 2;
    u16* ctxb = (u16*)(ws + off); off += (size_t)8192 * 1024 * 2;
    u16* xn   = (u16*)(ws + off); off += (size_t)4096 * 1024 * 2;   // reused as attn out
    u16* qb_  = (u16*)(ws + off); off += (size_t)4096 * 1024 * 2;
    u16* kb   = (u16*)(ws + off); off += (size_t)8192 * 1024 * 2;
    u16* vtb  = (u16*)(ws + off); off += (size_t)8192 * 1024 * 2;   // ~72MB
    u16* attnb = xn;  // xn dead after gemm_fused

    hipMemsetAsync(gsum, 0, 16, stream);
    absmean_k<<<dim3(128, 4), 256, 0, stream>>>(Wq, Wk, Wv, Wo, gsum);
    prep_k<<<16384, 256, 0, stream>>>(x, lng, lnb, xn, ctx, ctxb,
                                      Wq, Wk, Wv, Wo, wtq, wtk, wtv, wto, gsum);
    gemm_fused<<<1280, 256, 0, stream>>>(xn, ctxb, wtq, wtk, wtv, bq, bk, bv, gsum, qb_, kb, vtb);
    attn_k<<<dim3(64, 8), 256, 0, stream>>>(qb_, kb, vtb, attnb);
    gemm_o<<<512, 256, 0, stream>>>(attnb, wto, bo, gsum, x, out);
}